// Round 15
// baseline (179.557 us; speedup 1.0000x reference)
//
#include <hip/hip_runtime.h>
#include <hip/hip_bf16.h>

#define HIDN   64
#define NHEADS 8
#define DHEAD  8
#define NLAY   2
#define BB     4
#define SS     12
#define NNODE  512
#define NEDGE  8192
#define XELEMS (BB * SS * NNODE * 3)      // 73728
#define ROWS   (BB * SS * NNODE)          // 24576
#define QSCALE 0.51006967f                // (1/sqrt(8)) * log2(e): exp(x)=exp2(x*log2e)

typedef unsigned short u16;
typedef unsigned int   u32;
typedef __attribute__((ext_vector_type(4))) float f4;   // indexable float4
typedef __attribute__((ext_vector_type(8))) short s8v;  // 8 bf16 (4 VGPRs)

__device__ __forceinline__ float b2f(u16 u) {
    union { u32 i; float f; } c; c.i = ((u32)u) << 16; return c.f;
}
__device__ __forceinline__ u16 f2b(float f) {   // RNE float->bf16 bits
    union { float f; u32 i; } c; c.f = f;
    u32 r = c.i + 0x7FFFu + ((c.i >> 16) & 1u);
    return (u16)(r >> 16);
}
__device__ __forceinline__ u32 pk2(float a, float b) {
    return (u32)f2b(a) | ((u32)f2b(b) << 16);
}
// decode element i of a raw input tensor (fl=1 -> fp32, fl=0 -> bf16)
__device__ __forceinline__ float ld(const void* p, int i, int fl) {
    return fl ? ((const float*)p)[i] : b2f(((const u16*)p)[i]);
}

// -------- dtype detection FALLBACK (only if in_sizes is ambiguous) -----------
__global__ void detect_kernel(const u16* __restrict__ x, int* __restrict__ flag) {
    int i0 = blockIdx.x * 256 + threadIdx.x;
    int bad = 0;
    for (int i = i0; i < XELEMS; i += 64 * 256) {
        float v = fabsf(b2f(x[i]));
        if (!(v <= 100.f)) bad = 1;   // catches huge AND NaN
    }
    if (bad) atomicOr(flag, 1);       // flag=1 -> inputs are fp32
}

// ---------------- PREP: input_proj(bf16) + W packs(bf16) + mask/CSR ----------
// wb (temporal): [l][j 0..191][i 0..63] bf16 (B-frag loads 16B contiguous).
// whd (spatial, per-head): [l][hd][tile2][c 0..15][i 0..63] bf16;
//   tile0 cols = [Wk col hd*8+c | Wv col hd*8+(c-8)], tile1 = [Wq | zeros].
struct PrepArgs {
    const void* x; const void* Win; const void* bin; u16* h;
    const void* Wq[2]; const void* bq[2];
    const void* Wk[2]; const void* bk[2];
    const void* Wv[2]; const void* bv[2];
    u16* wb; u16* whd; float* bp[2];
    const int* ei; int* row_ptr; u16* col_idx;
};
__global__ __launch_bounds__(512) void prep_kernel(PrepArgs a, const int* __restrict__ flagp,
                                                   int flv) {
    __shared__ u32 msk[NNODE * 16];   // 32 KB (only used by last block)
    __shared__ int sc[512];
    int fl = (flv >= 0) ? flv : (*flagp != 0);
    int bid = blockIdx.x;
    int tid = threadIdx.x;
    if (bid < 384) {
        // ---- input projection: 8 consecutive h elems per thread, bf16 out
        int base = (bid * 512 + tid) * 8;     // row*64 + j0
        int row = base >> 6, j0 = base & 63;
        float x0 = ld(a.x, row * 3, fl);
        float x1 = ld(a.x, row * 3 + 1, fl);
        float x2 = ld(a.x, row * 3 + 2, fl);
        float o[8];
#pragma unroll
        for (int jj = 0; jj < 8; ++jj) {
            int j = j0 + jj;
            o[jj] = ld(a.bin, j, fl) + x0 * ld(a.Win, j * 3, fl)
                  + x1 * ld(a.Win, j * 3 + 1, fl) + x2 * ld(a.Win, j * 3 + 2, fl);
        }
        *(uint4*)&a.h[base] = make_uint4(pk2(o[0], o[1]), pk2(o[2], o[3]),
                                         pk2(o[4], o[5]), pk2(o[6], o[7]));
        return;
    }
    if (bid < 432) {
        // ---- temporal W full pack (p=1): dest l*12288 + j*64 + i
        int u = (bid - 384) * 512 + tid;  // 0..24575
        int l = u / 12288;
        int t = u - l * 12288;
        int j = t >> 6, i = t & 63;
        int cg = j >> 6, cc = j & 63;
        const void* W = (cg == 0) ? a.Wq[1] : (cg == 1) ? a.Wk[1] : a.Wv[1];
        a.wb[u] = f2b(ld(W, l * 4096 + cc * 64 + i, fl));
        // ---- bias (both p): first 768 u's cover 2p x 2l x 192
        if (u < 768) {
            int p2 = u / 384;
            int r3 = u - p2 * 384;
            int l2 = r3 / 192;
            int j2 = r3 - l2 * 192;
            int cg2 = j2 >> 6;
            const void* B = (cg2 == 0) ? a.bq[p2] : (cg2 == 1) ? a.bk[p2] : a.bv[p2];
            a.bp[p2][l2 * 192 + j2] = ld(B, l2 * 64 + (j2 & 63), fl);
        }
        return;
    }
    if (bid < 496) {
        // ---- spatial per-head pack: u -> [l][hd][tile][c][i]
        int u = (bid - 432) * 512 + tid;  // 0..32767
        int l    = u >> 14;
        int rem  = u & 16383;
        int hd   = rem >> 11;
        int rem2 = rem & 2047;
        int tile = rem2 >> 10;
        int rem3 = rem2 & 1023;
        int c    = rem3 >> 6;
        int i    = rem3 & 63;
        int j;
        if (tile == 0) j = (c < 8) ? (64 + hd * 8 + c) : (128 + hd * 8 + (c - 8));
        else           j = (c < 8) ? (hd * 8 + c) : -1;
        u16 val = 0;
        if (j >= 0) {
            int cg = j >> 6, cc = j & 63;
            const void* W = (cg == 0) ? a.Wq[0] : (cg == 1) ? a.Wk[0] : a.Wv[0];
            val = f2b(ld(W, l * 4096 + cc * 64 + i, fl));
        }
        a.whd[u] = val;
        return;
    }
    // ---- mask bitset (LDS) + CSR build, one 512-thread block
    for (int i = tid; i < NNODE * 16; i += 512) msk[i] = 0;
    __syncthreads();
    for (int e = tid; e < NEDGE; e += 512) {
        int r = a.ei[e];           // query row
        int m = a.ei[NEDGE + e];   // key col
        atomicOr(&msk[r * 16 + (m >> 5)], 1u << (m & 31));
    }
    __syncthreads();
    int n = tid;   // 0..511
    u32 w[16];
    int d = 0;
#pragma unroll
    for (int i = 0; i < 16; ++i) { w[i] = msk[n * 16 + i]; d += __popc(w[i]); }
    sc[n] = d;
    __syncthreads();
    for (int s = 1; s < 512; s <<= 1) {
        int v = (n >= s) ? sc[n - s] : 0;
        __syncthreads();
        sc[n] += v;
        __syncthreads();
    }
    int excl = sc[n] - d;
    a.row_ptr[n] = excl;
    if (n == 511) a.row_ptr[512] = sc[511];
    int base = excl;
#pragma unroll
    for (int i = 0; i < 16; ++i) {
        u32 m = w[i];
        while (m) {
            int b = __ffs(m) - 1;
            m &= m - 1;
            a.col_idx[base++] = (u16)(i * 32 + b);
        }
    }
}

// ---------------- FUSED spatial v3: conflict-free gather (stride-9 K/V) ------
// grid 384 = pair (bs*8+hd); 512 thr (8 waves). K/V GEMM once per pair.
// Ks/Vs rows padded to 9 floats: gcd(9,32)=1 -> random-m scalar gathers
// spread across all 32 banks (was 16-way conflict at stride 8 / b128).
// Same fragments/bias/MFMA order and FMA expression order as R14 ->
// bit-identical values.
__global__ __launch_bounds__(512) void spat_fused_kernel(
    const u16* __restrict__ hb, const u16* __restrict__ whd,
    const float* __restrict__ bp,
    const int* __restrict__ row_ptr, const u16* __restrict__ col_idx,
    u16* __restrict__ h2) {
    __shared__ float Ks[NNODE][9];                 // 18 KB
    __shared__ float Vs[NNODE][9];                 // 18 KB
    __shared__ float qS[NNODE][9];                 // 18 KB
    int pair = blockIdx.x;
    int bs = pair >> 3, hd = pair & 7;      // bs = b*S+s in [0,48)
    int t = threadIdx.x;
    int lane = t & 63, wv = t >> 6;         // 8 waves
    int lrow = lane & 15, kg = lane >> 4;
    const u16* hsl = hb + (long)bs * NNODE * HIDN;
    const u16* wkv = whd + hd * 2048;            // tile0: [k8|v8]
    const u16* wq  = whd + hd * 2048 + 1024;     // tile1: [q8|0]
    s8v bkv0 = *(const s8v*)(wkv + lrow * 64 + kg * 8);
    s8v bkv1 = *(const s8v*)(wkv + lrow * 64 + kg * 8 + 32);
    s8v bq0  = *(const s8v*)(wq  + lrow * 64 + kg * 8);
    s8v bq1  = *(const s8v*)(wq  + lrow * 64 + kg * 8 + 32);
    float biasKV = (lrow < 8) ? bp[64 + hd * 8 + lrow] : bp[128 + hd * 8 + (lrow & 7)];
    float biasQ  = bp[hd * 8 + (lrow & 7)];
    // K/V GEMM: 4 row-tiles per wave (8 waves cover all 32 tiles = 512 nodes)
#pragma unroll
    for (int s = 0; s < 4; ++s) {
        int rt = wv * 4 + s;                 // 0..31
        const u16* ap = hsl + (rt * 16 + lrow) * 64 + kg * 8;
        s8v ha0 = *(const s8v*)ap;
        s8v ha1 = *(const s8v*)(ap + 32);
        f4 acc = (f4){0.f, 0.f, 0.f, 0.f};
        acc = __builtin_amdgcn_mfma_f32_16x16x32_bf16(ha0, bkv0, acc, 0, 0, 0);
        acc = __builtin_amdgcn_mfma_f32_16x16x32_bf16(ha1, bkv1, acc, 0, 0, 0);
        int node = rt * 16 + kg * 4;
        if (lrow < 8) {
#pragma unroll
            for (int r = 0; r < 4; ++r) Ks[node + r][lrow] = acc[r] + biasKV;
        } else {
#pragma unroll
            for (int r = 0; r < 4; ++r) Vs[node + r][lrow & 7] = acc[r] + biasKV;
        }
    }
    // q GEMM: 4 row-tiles per wave (covers all 512 query rows)
#pragma unroll
    for (int s = 0; s < 4; ++s) {
        int rt = wv * 4 + s;                 // 0..31
        const u16* ap = hsl + (rt * 16 + lrow) * 64 + kg * 8;
        s8v ha0 = *(const s8v*)ap;
        s8v ha1 = *(const s8v*)(ap + 32);
        f4 acc = (f4){0.f, 0.f, 0.f, 0.f};
        acc = __builtin_amdgcn_mfma_f32_16x16x32_bf16(ha0, bq0, acc, 0, 0, 0);
        acc = __builtin_amdgcn_mfma_f32_16x16x32_bf16(ha1, bq1, acc, 0, 0, 0);
        if (lrow < 8) {
            int nl = rt * 16 + kg * 4;
#pragma unroll
            for (int r = 0; r < 4; ++r) qS[nl + r][lrow] = (acc[r] + biasQ) * QSCALE;
        }
    }
    __syncthreads();
    // ---- sparse attention, n = tid; scalar b32 gathers, same FMA order ----
    int n = t;
    float q0 = qS[n][0], q1 = qS[n][1], q2 = qS[n][2], q3 = qS[n][3];
    float q4 = qS[n][4], q5 = qS[n][5], q6 = qS[n][6], q7 = qS[n][7];
    int e0 = row_ptr[n], e1 = row_ptr[n + 1];
    float l = 0.f;
    float o0=0.f,o1=0.f,o2=0.f,o3=0.f,o4=0.f,o5=0.f,o6=0.f,o7=0.f;
    for (int e = e0; e < e1; ++e) {
        int m = col_idx[e];
        const float* kr = &Ks[m][0];
        float s = q0*kr[0] + q1*kr[1] + q2*kr[2] + q3*kr[3]
                + q4*kr[4] + q5*kr[5] + q6*kr[6] + q7*kr[7];
        float p = exp2f(s);          // q prescaled by (1/sqrt8)*log2e
        l += p;
        const float* vr = &Vs[m][0];
        o0 += p*vr[0]; o1 += p*vr[1]; o2 += p*vr[2]; o3 += p*vr[3];
        o4 += p*vr[4]; o5 += p*vr[5]; o6 += p*vr[6]; o7 += p*vr[7];
    }
    if (e1 == e0) {                  // fully-masked row: uniform mean(V)
        for (int m = 0; m < NNODE; ++m) {
            o0 += Vs[m][0]; o1 += Vs[m][1]; o2 += Vs[m][2]; o3 += Vs[m][3];
            o4 += Vs[m][4]; o5 += Vs[m][5]; o6 += Vs[m][6]; o7 += Vs[m][7];
        }
        l = (float)NNODE;
    }
    float inv = 1.f / l;
    u16* op = h2 + ((long)(bs * NNODE + n)) * HIDN + hd * 8;
    *(uint4*)op = make_uint4(pk2(o0*inv, o1*inv), pk2(o2*inv, o3*inv),
                             pk2(o4*inv, o5*inv), pk2(o6*inv, o7*inv));
}

// ---------------- FUSED temporal: MFMA qkv + attn (+ out_proj when last) -----
// grid 512 = (b, 4-node chunk); 384 thr (6 waves). Same structure as R14.
__global__ __launch_bounds__(384) void temp_fused_kernel(
    const u16* __restrict__ h2b, const u16* __restrict__ wb,
    const float* __restrict__ bp, u16* __restrict__ h,
    const void* __restrict__ Wout, const void* __restrict__ bout,
    void* __restrict__ out, const int* __restrict__ flagp, int flv, int last) {
    __shared__ float S[3][SS][32][9];   // 41472 B
    __shared__ u32 outS[4][32];         // packed bf16 pairs of last-step rows
    int b  = blockIdx.x >> 7;
    int n0 = (blockIdx.x & 127) * 4;
    int t = threadIdx.x;
    int lane = t & 63, wv = t >> 6;     // 6 waves
    int lrow = lane & 15, kg = lane >> 4;
    int rt  = wv >> 1;                  // 0..2
    int ct0 = (wv & 1) * 6;
    // A-frags: row gr = rt*16 + lrow -> (tt = gr>>2, nl = gr&3)
    int gr = rt * 16 + lrow;
    int tta = gr >> 2, nla = gr & 3;
    const u16* ap = h2b + ((long)((b * SS + tta) * NNODE) + n0 + nla) * HIDN + kg * 8;
    s8v haf0 = *(const s8v*)ap;
    s8v haf1 = *(const s8v*)(ap + 32);
#pragma unroll
    for (int s = 0; s < 6; ++s) {
        int ct = ct0 + s;
        const u16* wp = wb + (ct * 16 + lrow) * 64 + kg * 8;
        s8v wb0 = *(const s8v*)wp;
        s8v wb1 = *(const s8v*)(wp + 32);
        f4 acc = (f4){0.f, 0.f, 0.f, 0.f};
        acc = __builtin_amdgcn_mfma_f32_16x16x32_bf16(haf0, wb0, acc, 0, 0, 0);
        acc = __builtin_amdgcn_mfma_f32_16x16x32_bf16(haf1, wb1, acc, 0, 0, 0);
        int j = ct * 16 + lrow;
        float bb = bp[j];
        int tz = j >> 6, cc = j & 63, hd2 = cc >> 3, dh = cc & 7;
#pragma unroll
        for (int r = 0; r < 4; ++r) {
            int gr2 = rt * 16 + kg * 4 + r;
            S[tz][gr2 >> 2][(gr2 & 3) * 8 + hd2][dh] = acc[r] + bb;
        }
    }
    __syncthreads();
    // ---- temporal attention (R8-v4-proven) ----
    int sq = t >> 5, r = t & 31;        // r = nl*8+hd
    int nl = r >> 3, hd = r & 7;
    const float* qd = &S[0][sq][r][0];
    float q0=qd[0],q1=qd[1],q2=qd[2],q3=qd[3],q4=qd[4],q5=qd[5],q6=qd[6],q7=qd[7];
    float s[SS];
#pragma unroll
    for (int tt = 0; tt < SS; ++tt) {
        const float* kd = &S[1][tt][r][0];
        s[tt] = (q0 * kd[0] + q1 * kd[1] + q2 * kd[2] + q3 * kd[3] +
                 q4 * kd[4] + q5 * kd[5] + q6 * kd[6] + q7 * kd[7]) * QSCALE;
    }
    float mx = s[0];
#pragma unroll
    for (int tt = 1; tt < SS; ++tt) mx = fmaxf(mx, s[tt]);
    float l = 0.f;
#pragma unroll
    for (int tt = 0; tt < SS; ++tt) { s[tt] = exp2f(s[tt] - mx); l += s[tt]; }
    float a0=0.f,a1=0.f,a2=0.f,a3=0.f,a4=0.f,a5=0.f,a6=0.f,a7=0.f;
#pragma unroll
    for (int tt = 0; tt < SS; ++tt) {
        const float* vd = &S[2][tt][r][0];
        float e = s[tt];
        a0 += e * vd[0]; a1 += e * vd[1]; a2 += e * vd[2]; a3 += e * vd[3];
        a4 += e * vd[4]; a5 += e * vd[5]; a6 += e * vd[6]; a7 += e * vd[7];
    }
    float inv = 1.f / l;
    u32 p0 = pk2(a0*inv, a1*inv), p1 = pk2(a2*inv, a3*inv);
    u32 p2 = pk2(a4*inv, a5*inv), p3 = pk2(a6*inv, a7*inv);
    u16* op = h + ((long)((b * SS + sq) * NNODE) + n0 + nl) * HIDN + hd * 8;
    *(uint4*)op = make_uint4(p0, p1, p2, p3);
    // ---- fused out projection (last layer only) ----
    if (last) {
        if (sq == SS - 1) {
            outS[nl][hd * 4 + 0] = p0;
            outS[nl][hd * 4 + 1] = p1;
            outS[nl][hd * 4 + 2] = p2;
            outS[nl][hd * 4 + 3] = p3;
        }
        __syncthreads();
        if (t < 12) {
            int fl = (flv >= 0) ? flv : (*flagp != 0);
            int c = t % 3, nl2 = t / 3;
            float acc = ld(bout, c, fl);
#pragma unroll
            for (int i = 0; i < HIDN; i += 8) {
                // same decode+accumulate order as old out_proj_kernel
                u32 hw0 = outS[nl2][i / 2 + 0];
                u32 hw1 = outS[nl2][i / 2 + 1];
                u32 hw2 = outS[nl2][i / 2 + 2];
                u32 hw3 = outS[nl2][i / 2 + 3];
                const u32 hw[4] = {hw0, hw1, hw2, hw3};
#pragma unroll
                for (int j2 = 0; j2 < 4; ++j2) {
                    float hlo = b2f((u16)(hw[j2] & 0xFFFF));
                    float hhi = b2f((u16)(hw[j2] >> 16));
                    acc += hlo * ld(Wout, c * 64 + i + j2 * 2,     fl)
                         + hhi * ld(Wout, c * 64 + i + j2 * 2 + 1, fl);
                }
            }
            int ti = (b * NNODE + n0 + nl2) * 3 + c;
            if (fl) ((float*)out)[ti] = acc;
            else    ((__hip_bfloat16*)out)[ti] = __float2bfloat16(acc);
        }
    }
}

extern "C" void kernel_launch(void* const* d_in, const int* in_sizes, int n_in,
                              void* d_out, int out_size, void* d_ws, size_t ws_size,
                              hipStream_t stream) {
    const int* ei = (const int*)d_in[1];

    float* ws = (float*)d_ws;
    int*   flag    = (int*)ws;                    // 64 floats reserved
    int*   row_ptr = (int*)(ws + 64);             // 513 ints (reserve 576)
    u16*   col_idx = (u16*)(ws + 640);            // 8192 u16 (4096 float slots)
    u16*   wb16  = (u16*)(ws + 4736);             // temporal pack: 24576 u16 (12288 fl)
    u16*   whd16 = (u16*)(ws + 4736 + 12288);     // spatial per-head: 32768 u16 (16384 fl)
    float* bsp   = ws + 4736 + 12288 + 16384;     // 2*192
    float* btp   = bsp + 384;                     // 2*192
    u16*   hb16  = (u16*)(btp + 384);             // ROWS*64 u16
    u16*   h2b16 = hb16 + ROWS * HIDN;            // ROWS*64 u16

    // dtype from host-visible byte sizes; runtime-detect only if ambiguous
    int flv = -1;
    if (in_sizes) {
        if (in_sizes[0] == XELEMS * 2) flv = 0;        // bf16
        else if (in_sizes[0] == XELEMS * 4) flv = 1;   // fp32
    }
    if (flv < 0) {   // ambiguous: runtime detect (memset + detect only here)
        (void)hipMemsetAsync(flag, 0, sizeof(int), stream);
        detect_kernel<<<64, 256, 0, stream>>>((const u16*)d_in[0], flag);
    }

    PrepArgs pr;
    pr.x = d_in[0]; pr.Win = d_in[2]; pr.bin = d_in[3]; pr.h = hb16;
    pr.Wq[0] = d_in[4];  pr.bq[0] = d_in[5];
    pr.Wk[0] = d_in[6];  pr.bk[0] = d_in[7];
    pr.Wv[0] = d_in[8];  pr.bv[0] = d_in[9];
    pr.Wq[1] = d_in[10]; pr.bq[1] = d_in[11];
    pr.Wk[1] = d_in[12]; pr.bk[1] = d_in[13];
    pr.Wv[1] = d_in[14]; pr.bv[1] = d_in[15];
    pr.wb = wb16; pr.whd = whd16; pr.bp[0] = bsp; pr.bp[1] = btp;
    pr.ei = ei; pr.row_ptr = row_ptr; pr.col_idx = col_idx;
    prep_kernel<<<384 + 48 + 64 + 1, 512, 0, stream>>>(pr, flag, flv);

    for (int l = 0; l < NLAY; ++l) {
        spat_fused_kernel<<<BB * SS * NHEADS, 512, 0, stream>>>(
            hb16, whd16 + l * 16384, bsp + l * 192, row_ptr, col_idx, h2b16);
        temp_fused_kernel<<<BB * (NNODE / 4), 384, 0, stream>>>(
            h2b16, wb16 + l * 12288, btp + l * 192, hb16,
            d_in[16], d_in[17], d_out, flag, flv, (l == NLAY - 1) ? 1 : 0);
    }
}

// Round 16
// 173.762 us; speedup vs baseline: 1.0333x; 1.0333x over previous
//
#include <hip/hip_runtime.h>
#include <hip/hip_bf16.h>

#define HIDN   64
#define NHEADS 8
#define DHEAD  8
#define NLAY   2
#define BB     4
#define SS     12
#define NNODE  512
#define NEDGE  8192
#define XELEMS (BB * SS * NNODE * 3)      // 73728
#define ROWS   (BB * SS * NNODE)          // 24576
#define QSCALE 0.51006967f                // (1/sqrt(8)) * log2(e): exp(x)=exp2(x*log2e)

typedef unsigned short u16;
typedef unsigned int   u32;
typedef __attribute__((ext_vector_type(4))) float f4;   // indexable float4
typedef __attribute__((ext_vector_type(8))) short s8v;  // 8 bf16 (4 VGPRs)

__device__ __forceinline__ float b2f(u16 u) {
    union { u32 i; float f; } c; c.i = ((u32)u) << 16; return c.f;
}
__device__ __forceinline__ u16 f2b(float f) {   // RNE float->bf16 bits
    union { float f; u32 i; } c; c.f = f;
    u32 r = c.i + 0x7FFFu + ((c.i >> 16) & 1u);
    return (u16)(r >> 16);
}
__device__ __forceinline__ u32 pk2(float a, float b) {
    return (u32)f2b(a) | ((u32)f2b(b) << 16);
}
// decode element i of a raw input tensor (fl=1 -> fp32, fl=0 -> bf16)
__device__ __forceinline__ float ld(const void* p, int i, int fl) {
    return fl ? ((const float*)p)[i] : b2f(((const u16*)p)[i]);
}

// -------- dtype detection FALLBACK (only if in_sizes is ambiguous) -----------
__global__ void detect_kernel(const u16* __restrict__ x, int* __restrict__ flag) {
    int i0 = blockIdx.x * 256 + threadIdx.x;
    int bad = 0;
    for (int i = i0; i < XELEMS; i += 64 * 256) {
        float v = fabsf(b2f(x[i]));
        if (!(v <= 100.f)) bad = 1;   // catches huge AND NaN
    }
    if (bad) atomicOr(flag, 1);       // flag=1 -> inputs are fp32
}

// ---------------- PREP: input_proj(bf16) + W packs(bf16) + mask/CSR ----------
// wb (temporal): [l][j 0..191][i 0..63] bf16 (B-frag loads 16B contiguous).
// whd (spatial, per-head): [l][hd][tile2][c 0..15][i 0..63] bf16;
//   tile0 cols = [Wk col hd*8+c | Wv col hd*8+(c-8)], tile1 = [Wq | zeros].
struct PrepArgs {
    const void* x; const void* Win; const void* bin; u16* h;
    const void* Wq[2]; const void* bq[2];
    const void* Wk[2]; const void* bk[2];
    const void* Wv[2]; const void* bv[2];
    u16* wb; u16* whd; float* bp[2];
    const int* ei; int* row_ptr; u16* col_idx;
};
__global__ __launch_bounds__(512) void prep_kernel(PrepArgs a, const int* __restrict__ flagp,
                                                   int flv) {
    __shared__ u32 msk[NNODE * 16];   // 32 KB (only used by last block)
    __shared__ int sc[512];
    int fl = (flv >= 0) ? flv : (*flagp != 0);
    int bid = blockIdx.x;
    int tid = threadIdx.x;
    if (bid < 384) {
        // ---- input projection: 8 consecutive h elems per thread, bf16 out
        int base = (bid * 512 + tid) * 8;     // row*64 + j0
        int row = base >> 6, j0 = base & 63;
        float x0 = ld(a.x, row * 3, fl);
        float x1 = ld(a.x, row * 3 + 1, fl);
        float x2 = ld(a.x, row * 3 + 2, fl);
        float o[8];
#pragma unroll
        for (int jj = 0; jj < 8; ++jj) {
            int j = j0 + jj;
            o[jj] = ld(a.bin, j, fl) + x0 * ld(a.Win, j * 3, fl)
                  + x1 * ld(a.Win, j * 3 + 1, fl) + x2 * ld(a.Win, j * 3 + 2, fl);
        }
        *(uint4*)&a.h[base] = make_uint4(pk2(o[0], o[1]), pk2(o[2], o[3]),
                                         pk2(o[4], o[5]), pk2(o[6], o[7]));
        return;
    }
    if (bid < 432) {
        // ---- temporal W full pack (p=1): dest l*12288 + j*64 + i
        int u = (bid - 384) * 512 + tid;  // 0..24575
        int l = u / 12288;
        int t = u - l * 12288;
        int j = t >> 6, i = t & 63;
        int cg = j >> 6, cc = j & 63;
        const void* W = (cg == 0) ? a.Wq[1] : (cg == 1) ? a.Wk[1] : a.Wv[1];
        a.wb[u] = f2b(ld(W, l * 4096 + cc * 64 + i, fl));
        // ---- bias (both p): first 768 u's cover 2p x 2l x 192
        if (u < 768) {
            int p2 = u / 384;
            int r3 = u - p2 * 384;
            int l2 = r3 / 192;
            int j2 = r3 - l2 * 192;
            int cg2 = j2 >> 6;
            const void* B = (cg2 == 0) ? a.bq[p2] : (cg2 == 1) ? a.bk[p2] : a.bv[p2];
            a.bp[p2][l2 * 192 + j2] = ld(B, l2 * 64 + (j2 & 63), fl);
        }
        return;
    }
    if (bid < 496) {
        // ---- spatial per-head pack: u -> [l][hd][tile][c][i]
        int u = (bid - 432) * 512 + tid;  // 0..32767
        int l    = u >> 14;
        int rem  = u & 16383;
        int hd   = rem >> 11;
        int rem2 = rem & 2047;
        int tile = rem2 >> 10;
        int rem3 = rem2 & 1023;
        int c    = rem3 >> 6;
        int i    = rem3 & 63;
        int j;
        if (tile == 0) j = (c < 8) ? (64 + hd * 8 + c) : (128 + hd * 8 + (c - 8));
        else           j = (c < 8) ? (hd * 8 + c) : -1;
        u16 val = 0;
        if (j >= 0) {
            int cg = j >> 6, cc = j & 63;
            const void* W = (cg == 0) ? a.Wq[0] : (cg == 1) ? a.Wk[0] : a.Wv[0];
            val = f2b(ld(W, l * 4096 + cc * 64 + i, fl));
        }
        a.whd[u] = val;
        return;
    }
    // ---- mask bitset (LDS) + CSR build, one 512-thread block
    for (int i = tid; i < NNODE * 16; i += 512) msk[i] = 0;
    __syncthreads();
    for (int e = tid; e < NEDGE; e += 512) {
        int r = a.ei[e];           // query row
        int m = a.ei[NEDGE + e];   // key col
        atomicOr(&msk[r * 16 + (m >> 5)], 1u << (m & 31));
    }
    __syncthreads();
    int n = tid;   // 0..511
    u32 w[16];
    int d = 0;
#pragma unroll
    for (int i = 0; i < 16; ++i) { w[i] = msk[n * 16 + i]; d += __popc(w[i]); }
    sc[n] = d;
    __syncthreads();
    for (int s = 1; s < 512; s <<= 1) {
        int v = (n >= s) ? sc[n - s] : 0;
        __syncthreads();
        sc[n] += v;
        __syncthreads();
    }
    int excl = sc[n] - d;
    a.row_ptr[n] = excl;
    if (n == 511) a.row_ptr[512] = sc[511];
    int base = excl;
#pragma unroll
    for (int i = 0; i < 16; ++i) {
        u32 m = w[i];
        while (m) {
            int b = __ffs(m) - 1;
            m &= m - 1;
            a.col_idx[base++] = (u16)(i * 32 + b);
        }
    }
}

// ---------------- FUSED spatial v2 (R14-proven): dedup K/V GEMM --------------
// grid 384 = pair (bs*8+hd); 512 thr (8 waves). K/V computed once per pair.
// Per wave: 4 KV row-tiles x2 MFMA + 4 q row-tiles x2 MFMA. C (m89 mapping)
// -> Ks/Vs[512][8], qS[512][9]. ONE barrier, then sparse-CSR attention with
// float4 gathers (R14 layout: stride-8, b128 reads -- empirically faster than
// R15's stride-9 scalar variant despite bank conflicts).
__global__ __launch_bounds__(512) void spat_fused_kernel(
    const u16* __restrict__ hb, const u16* __restrict__ whd,
    const float* __restrict__ bp,
    const int* __restrict__ row_ptr, const u16* __restrict__ col_idx,
    u16* __restrict__ h2) {
    __shared__ __align__(16) float Ks[NNODE][8];   // 16 KB
    __shared__ __align__(16) float Vs[NNODE][8];   // 16 KB
    __shared__ float qS[NNODE][9];                 // 18 KB
    int pair = blockIdx.x;
    int bs = pair >> 3, hd = pair & 7;      // bs = b*S+s in [0,48)
    int t = threadIdx.x;
    int lane = t & 63, wv = t >> 6;         // 8 waves
    int lrow = lane & 15, kg = lane >> 4;
    const u16* hsl = hb + (long)bs * NNODE * HIDN;
    const u16* wkv = whd + hd * 2048;            // tile0: [k8|v8]
    const u16* wq  = whd + hd * 2048 + 1024;     // tile1: [q8|0]
    s8v bkv0 = *(const s8v*)(wkv + lrow * 64 + kg * 8);
    s8v bkv1 = *(const s8v*)(wkv + lrow * 64 + kg * 8 + 32);
    s8v bq0  = *(const s8v*)(wq  + lrow * 64 + kg * 8);
    s8v bq1  = *(const s8v*)(wq  + lrow * 64 + kg * 8 + 32);
    float biasKV = (lrow < 8) ? bp[64 + hd * 8 + lrow] : bp[128 + hd * 8 + (lrow & 7)];
    float biasQ  = bp[hd * 8 + (lrow & 7)];
    // K/V GEMM: 4 row-tiles per wave (8 waves cover all 32 tiles = 512 nodes)
#pragma unroll
    for (int s = 0; s < 4; ++s) {
        int rt = wv * 4 + s;                 // 0..31
        const u16* ap = hsl + (rt * 16 + lrow) * 64 + kg * 8;
        s8v ha0 = *(const s8v*)ap;
        s8v ha1 = *(const s8v*)(ap + 32);
        f4 acc = (f4){0.f, 0.f, 0.f, 0.f};
        acc = __builtin_amdgcn_mfma_f32_16x16x32_bf16(ha0, bkv0, acc, 0, 0, 0);
        acc = __builtin_amdgcn_mfma_f32_16x16x32_bf16(ha1, bkv1, acc, 0, 0, 0);
        int node = rt * 16 + kg * 4;
        if (lrow < 8) {
#pragma unroll
            for (int r = 0; r < 4; ++r) Ks[node + r][lrow] = acc[r] + biasKV;
        } else {
#pragma unroll
            for (int r = 0; r < 4; ++r) Vs[node + r][lrow & 7] = acc[r] + biasKV;
        }
    }
    // q GEMM: 4 row-tiles per wave (covers all 512 query rows)
#pragma unroll
    for (int s = 0; s < 4; ++s) {
        int rt = wv * 4 + s;                 // 0..31
        const u16* ap = hsl + (rt * 16 + lrow) * 64 + kg * 8;
        s8v ha0 = *(const s8v*)ap;
        s8v ha1 = *(const s8v*)(ap + 32);
        f4 acc = (f4){0.f, 0.f, 0.f, 0.f};
        acc = __builtin_amdgcn_mfma_f32_16x16x32_bf16(ha0, bq0, acc, 0, 0, 0);
        acc = __builtin_amdgcn_mfma_f32_16x16x32_bf16(ha1, bq1, acc, 0, 0, 0);
        if (lrow < 8) {
            int nl = rt * 16 + kg * 4;
#pragma unroll
            for (int r = 0; r < 4; ++r) qS[nl + r][lrow] = (acc[r] + biasQ) * QSCALE;
        }
    }
    __syncthreads();
    // ---- sparse attention (R8/R14-proven), n = tid over all 512 queries ----
    int n = t;
    float4 qa = make_float4(qS[n][0], qS[n][1], qS[n][2], qS[n][3]);
    float4 qc = make_float4(qS[n][4], qS[n][5], qS[n][6], qS[n][7]);
    int e0 = row_ptr[n], e1 = row_ptr[n + 1];
    float l = 0.f;
    float o0=0.f,o1=0.f,o2=0.f,o3=0.f,o4=0.f,o5=0.f,o6=0.f,o7=0.f;
    for (int e = e0; e < e1; ++e) {
        int m = col_idx[e];
        float4 ka = *(const float4*)&Ks[m][0];
        float4 kc = *(const float4*)&Ks[m][4];
        float s = qa.x*ka.x + qa.y*ka.y + qa.z*ka.z + qa.w*ka.w
                + qc.x*kc.x + qc.y*kc.y + qc.z*kc.z + qc.w*kc.w;
        float p = exp2f(s);          // q prescaled by (1/sqrt8)*log2e
        l += p;
        float4 va = *(const float4*)&Vs[m][0];
        float4 vc = *(const float4*)&Vs[m][4];
        o0 += p*va.x; o1 += p*va.y; o2 += p*va.z; o3 += p*va.w;
        o4 += p*vc.x; o5 += p*vc.y; o6 += p*vc.z; o7 += p*vc.w;
    }
    if (e1 == e0) {                  // fully-masked row: uniform mean(V)
        for (int m = 0; m < NNODE; ++m) {
            o0 += Vs[m][0]; o1 += Vs[m][1]; o2 += Vs[m][2]; o3 += Vs[m][3];
            o4 += Vs[m][4]; o5 += Vs[m][5]; o6 += Vs[m][6]; o7 += Vs[m][7];
        }
        l = (float)NNODE;
    }
    float inv = 1.f / l;
    u16* op = h2 + ((long)(bs * NNODE + n)) * HIDN + hd * 8;
    *(uint4*)op = make_uint4(pk2(o0*inv, o1*inv), pk2(o2*inv, o3*inv),
                             pk2(o4*inv, o5*inv), pk2(o6*inv, o7*inv));
}

// ---------------- FUSED temporal: MFMA qkv + attn (+ out_proj when last) -----
// grid 512 = (b, 4-node chunk); 384 thr (6 waves). Same structure as R14.
__global__ __launch_bounds__(384) void temp_fused_kernel(
    const u16* __restrict__ h2b, const u16* __restrict__ wb,
    const float* __restrict__ bp, u16* __restrict__ h,
    const void* __restrict__ Wout, const void* __restrict__ bout,
    void* __restrict__ out, const int* __restrict__ flagp, int flv, int last) {
    __shared__ float S[3][SS][32][9];   // 41472 B
    __shared__ u32 outS[4][32];         // packed bf16 pairs of last-step rows
    int b  = blockIdx.x >> 7;
    int n0 = (blockIdx.x & 127) * 4;
    int t = threadIdx.x;
    int lane = t & 63, wv = t >> 6;     // 6 waves
    int lrow = lane & 15, kg = lane >> 4;
    int rt  = wv >> 1;                  // 0..2
    int ct0 = (wv & 1) * 6;
    // A-frags: row gr = rt*16 + lrow -> (tt = gr>>2, nl = gr&3)
    int gr = rt * 16 + lrow;
    int tta = gr >> 2, nla = gr & 3;
    const u16* ap = h2b + ((long)((b * SS + tta) * NNODE) + n0 + nla) * HIDN + kg * 8;
    s8v haf0 = *(const s8v*)ap;
    s8v haf1 = *(const s8v*)(ap + 32);
#pragma unroll
    for (int s = 0; s < 6; ++s) {
        int ct = ct0 + s;
        const u16* wp = wb + (ct * 16 + lrow) * 64 + kg * 8;
        s8v wb0 = *(const s8v*)wp;
        s8v wb1 = *(const s8v*)(wp + 32);
        f4 acc = (f4){0.f, 0.f, 0.f, 0.f};
        acc = __builtin_amdgcn_mfma_f32_16x16x32_bf16(haf0, wb0, acc, 0, 0, 0);
        acc = __builtin_amdgcn_mfma_f32_16x16x32_bf16(haf1, wb1, acc, 0, 0, 0);
        int j = ct * 16 + lrow;
        float bb = bp[j];
        int tz = j >> 6, cc = j & 63, hd2 = cc >> 3, dh = cc & 7;
#pragma unroll
        for (int r = 0; r < 4; ++r) {
            int gr2 = rt * 16 + kg * 4 + r;
            S[tz][gr2 >> 2][(gr2 & 3) * 8 + hd2][dh] = acc[r] + bb;
        }
    }
    __syncthreads();
    // ---- temporal attention (R8-v4-proven) ----
    int sq = t >> 5, r = t & 31;        // r = nl*8+hd
    int nl = r >> 3, hd = r & 7;
    const float* qd = &S[0][sq][r][0];
    float q0=qd[0],q1=qd[1],q2=qd[2],q3=qd[3],q4=qd[4],q5=qd[5],q6=qd[6],q7=qd[7];
    float s[SS];
#pragma unroll
    for (int tt = 0; tt < SS; ++tt) {
        const float* kd = &S[1][tt][r][0];
        s[tt] = (q0 * kd[0] + q1 * kd[1] + q2 * kd[2] + q3 * kd[3] +
                 q4 * kd[4] + q5 * kd[5] + q6 * kd[6] + q7 * kd[7]) * QSCALE;
    }
    float mx = s[0];
#pragma unroll
    for (int tt = 1; tt < SS; ++tt) mx = fmaxf(mx, s[tt]);
    float l = 0.f;
#pragma unroll
    for (int tt = 0; tt < SS; ++tt) { s[tt] = exp2f(s[tt] - mx); l += s[tt]; }
    float a0=0.f,a1=0.f,a2=0.f,a3=0.f,a4=0.f,a5=0.f,a6=0.f,a7=0.f;
#pragma unroll
    for (int tt = 0; tt < SS; ++tt) {
        const float* vd = &S[2][tt][r][0];
        float e = s[tt];
        a0 += e * vd[0]; a1 += e * vd[1]; a2 += e * vd[2]; a3 += e * vd[3];
        a4 += e * vd[4]; a5 += e * vd[5]; a6 += e * vd[6]; a7 += e * vd[7];
    }
    float inv = 1.f / l;
    u32 p0 = pk2(a0*inv, a1*inv), p1 = pk2(a2*inv, a3*inv);
    u32 p2 = pk2(a4*inv, a5*inv), p3 = pk2(a6*inv, a7*inv);
    u16* op = h + ((long)((b * SS + sq) * NNODE) + n0 + nl) * HIDN + hd * 8;
    *(uint4*)op = make_uint4(p0, p1, p2, p3);
    // ---- fused out projection (last layer only) ----
    if (last) {
        if (sq == SS - 1) {
            outS[nl][hd * 4 + 0] = p0;
            outS[nl][hd * 4 + 1] = p1;
            outS[nl][hd * 4 + 2] = p2;
            outS[nl][hd * 4 + 3] = p3;
        }
        __syncthreads();
        if (t < 12) {
            int fl = (flv >= 0) ? flv : (*flagp != 0);
            int c = t % 3, nl2 = t / 3;
            float acc = ld(bout, c, fl);
#pragma unroll
            for (int i = 0; i < HIDN; i += 8) {
                // same decode+accumulate order as old out_proj_kernel
                u32 hw0 = outS[nl2][i / 2 + 0];
                u32 hw1 = outS[nl2][i / 2 + 1];
                u32 hw2 = outS[nl2][i / 2 + 2];
                u32 hw3 = outS[nl2][i / 2 + 3];
                const u32 hw[4] = {hw0, hw1, hw2, hw3};
#pragma unroll
                for (int j2 = 0; j2 < 4; ++j2) {
                    float hlo = b2f((u16)(hw[j2] & 0xFFFF));
                    float hhi = b2f((u16)(hw[j2] >> 16));
                    acc += hlo * ld(Wout, c * 64 + i + j2 * 2,     fl)
                         + hhi * ld(Wout, c * 64 + i + j2 * 2 + 1, fl);
                }
            }
            int ti = (b * NNODE + n0 + nl2) * 3 + c;
            if (fl) ((float*)out)[ti] = acc;
            else    ((__hip_bfloat16*)out)[ti] = __float2bfloat16(acc);
        }
    }
}

extern "C" void kernel_launch(void* const* d_in, const int* in_sizes, int n_in,
                              void* d_out, int out_size, void* d_ws, size_t ws_size,
                              hipStream_t stream) {
    const int* ei = (const int*)d_in[1];

    float* ws = (float*)d_ws;
    int*   flag    = (int*)ws;                    // 64 floats reserved
    int*   row_ptr = (int*)(ws + 64);             // 513 ints (reserve 576)
    u16*   col_idx = (u16*)(ws + 640);            // 8192 u16 (4096 float slots)
    u16*   wb16  = (u16*)(ws + 4736);             // temporal pack: 24576 u16 (12288 fl)
    u16*   whd16 = (u16*)(ws + 4736 + 12288);     // spatial per-head: 32768 u16 (16384 fl)
    float* bsp   = ws + 4736 + 12288 + 16384;     // 2*192
    float* btp   = bsp + 384;                     // 2*192
    u16*   hb16  = (u16*)(btp + 384);             // ROWS*64 u16
    u16*   h2b16 = hb16 + ROWS * HIDN;            // ROWS*64 u16

    // dtype from host-visible byte sizes; runtime-detect only if ambiguous
    int flv = -1;
    if (in_sizes) {
        if (in_sizes[0] == XELEMS * 2) flv = 0;        // bf16
        else if (in_sizes[0] == XELEMS * 4) flv = 1;   // fp32
    }
    if (flv < 0) {   // ambiguous: runtime detect (memset + detect only here)
        (void)hipMemsetAsync(flag, 0, sizeof(int), stream);
        detect_kernel<<<64, 256, 0, stream>>>((const u16*)d_in[0], flag);
    }

    PrepArgs pr;
    pr.x = d_in[0]; pr.Win = d_in[2]; pr.bin = d_in[3]; pr.h = hb16;
    pr.Wq[0] = d_in[4];  pr.bq[0] = d_in[5];
    pr.Wk[0] = d_in[6];  pr.bk[0] = d_in[7];
    pr.Wv[0] = d_in[8];  pr.bv[0] = d_in[9];
    pr.Wq[1] = d_in[10]; pr.bq[1] = d_in[11];
    pr.Wk[1] = d_in[12]; pr.bk[1] = d_in[13];
    pr.Wv[1] = d_in[14]; pr.bv[1] = d_in[15];
    pr.wb = wb16; pr.whd = whd16; pr.bp[0] = bsp; pr.bp[1] = btp;
    pr.ei = ei; pr.row_ptr = row_ptr; pr.col_idx = col_idx;
    prep_kernel<<<384 + 48 + 64 + 1, 512, 0, stream>>>(pr, flag, flv);

    for (int l = 0; l < NLAY; ++l) {
        spat_fused_kernel<<<BB * SS * NHEADS, 512, 0, stream>>>(
            hb16, whd16 + l * 16384, bsp + l * 192, row_ptr, col_idx, h2b16);
        temp_fused_kernel<<<BB * (NNODE / 4), 384, 0, stream>>>(
            h2b16, wb16 + l * 12288, btp + l * 192, hb16,
            d_in[16], d_in[17], d_out, flag, flv, (l == NLAY - 1) ? 1 : 0);
    }
}